// Round 19
// baseline (89.318 us; speedup 1.0000x reference)
//
#include <hip/hip_runtime.h>
#include <hip/hip_bf16.h>

#define N_B   4
#define C_IN  128
#define HWSZ  4096
#define C_M   256

typedef __attribute__((ext_vector_type(8))) short          s16x8;
typedef __attribute__((ext_vector_type(8))) unsigned short u16x8;
typedef __attribute__((ext_vector_type(4))) unsigned short u16x4;
typedef __attribute__((ext_vector_type(4))) float          f32x4;

__device__ __forceinline__ unsigned short f2bf(float f) {
    union { float f; unsigned u; } v; v.f = f;
    unsigned r = v.u + 0x7fffu + ((v.u >> 16) & 1u);   // RNE
    return (unsigned short)(r >> 16);
}
__device__ __forceinline__ float bf2f(unsigned short u) {
    union { unsigned u; float f; } v; v.u = ((unsigned)u) << 16; return v.f;
}

// ---------------------------------------------------------------------------
// K1: weight prep only (img transpose fused into conv1).
//  w1f[z2][cc4][tap9][g9][lane64][j8]; row=g*16+(lane&15), ci=cc*32+(lane>>4)*8+j
//  w2f[uvt16][k9][ks8][lg4][ln16][j8] = 0.25*mk_w2[(k*256+uvt*16+ln)*256+ks*32+lg*8+j]
// ---------------------------------------------------------------------------
__global__ void __launch_bounds__(256)
prep_weights(const float* __restrict__ mk_w1, const float* __restrict__ fh_w1,
             const float* __restrict__ mk_w2,
             unsigned short* __restrict__ w1f, unsigned short* __restrict__ w2f)
{
    int i = blockIdx.x * 256 + threadIdx.x;
    if (i < 2304 * 256) {
        int uvt = i / 36864;
        int r   = i - uvt * 36864;
        int k   = r / 4096;
        int r2  = r - k * 4096;
        int ks  = r2 >> 9;
        int lg  = (r2 >> 7) & 3;
        int ln  = (r2 >> 3) & 15;
        int j   = r2 & 7;
        w2f[i] = f2bf(0.25f * mk_w2[(size_t)(k * 256 + uvt * 16 + ln) * 256 + ks * 32 + lg * 8 + j]);
    }
    if (i < 2 * 4 * 9 * 9 * 512) {
        int z   = i / 165888;
        int r   = i - z * 165888;
        int cc  = r / 41472;
        int r2  = r - cc * 41472;
        int tap = r2 / 4608;
        int r3  = r2 - tap * 4608;
        int g   = r3 / 512;
        int r4  = r3 - g * 512;
        int lane = r4 >> 3, j = r4 & 7;
        int lg = lane >> 4, ln = lane & 15;
        int row = g * 16 + ln;
        int ci  = cc * 32 + lg * 8 + j;
        float w = 0.f;
        if (z == 0) {
            if (row < 128)      w = mk_w1[((size_t)row * C_IN + ci) * 9 + tap];
            else if (row < 130) w = fh_w1[((size_t)(row - 128) * C_IN + ci) * 9 + tap];
        } else {
            if (row < 128)      w = mk_w1[((size_t)(128 + row) * C_IN + ci) * 9 + tap];
        }
        w1f[i] = f2bf(w);
    }
}

// ---------------------------------------------------------------------------
// K2: conv1 implicit-GEMM 3x3. R19: stages img DIRECTLY (fp32, ci-major
// coalesced reads + f2bf) -- no imgT pass. Rest unchanged (known-good).
// ---------------------------------------------------------------------------
__global__ void __launch_bounds__(512, 4)
conv1_mfma(const float* __restrict__ img,
           const unsigned short* __restrict__ w1f,
           const float* __restrict__ mk_b1, const float* __restrict__ fh_b1,
           unsigned short* __restrict__ m_frag, float* __restrict__ h_pre,
           float* __restrict__ ps_s, float* __restrict__ ps_s2)
{
    __shared__ unsigned short s_img[3][66][40];   // 15,840 B
    __shared__ float s_bias[144];
    __shared__ float s_ps[2][144], s_ps2[2][144];

    const int hw = blockIdx.x;
    const int xcd = hw & 7, slot = hw >> 3;
    const int lid = xcd * 64 + slot;
    const int n = lid >> 7, h = (lid >> 1) & 63, z = lid & 1;
    const int hn = n * 64 + h;

    const int tid = threadIdx.x;
    const int wv = tid >> 6, lane = tid & 63;
    const int lg = lane >> 4, ln = lane & 15;
    const int gq = wv >> 1, half = wv & 1;
    const int g0 = z ? (gq * 2) : ((int[4]){0, 3, 5, 7})[gq];
    const int gn = z ? 2 : ((int[4]){3, 2, 2, 2})[gq];

    if (tid < 144) {
        float b = 0.f;
        if (z == 0) {
            if (tid < 128)      b = mk_b1[tid];
            else if (tid < 130) b = fh_b1[tid - 128];
        } else if (tid < 128)   b = mk_b1[128 + tid];
        s_bias[tid] = b;
    }

    f32x4 acc[3][2];
#pragma unroll
    for (int g = 0; g < 3; ++g)
#pragma unroll
        for (int q = 0; q < 2; ++q) acc[g][q] = (f32x4){0.f, 0.f, 0.f, 0.f};

    for (int cc = 0; cc < 4; ++cc) {
        __syncthreads();
        // stage rows h-1..h+1, cols -1..64, 32 ci: ci-major loop so lanes
        // read consecutive gx within one (ci,row) segment (coalesced fp32).
        for (int i = tid; i < 32 * 3 * 66; i += 512) {
            int ci  = i / 198;
            int rem = i - ci * 198;
            int r   = rem / 66;
            int c   = rem - r * 66;
            int gy = h - 1 + r, gx = c - 1;
            float v = 0.f;
            if ((unsigned)gy < 64u && (unsigned)gx < 64u)
                v = img[(((size_t)(n * C_IN + cc * 32 + ci)) * 64 + gy) * 64 + gx];
            s_img[r][c][ci] = f2bf(v);
        }
        __syncthreads();

        const unsigned short* wfp = w1f + (size_t)(z * 4 + cc) * 81 * 512 + lane * 8;
#pragma unroll
        for (int tap = 0; tap < 9; ++tap) {
            const int dy = tap / 3, dx = tap % 3;
            s16x8 bf[2];
#pragma unroll
            for (int q = 0; q < 2; ++q)
                bf[q] = *(const s16x8*)&s_img[dy][half * 32 + q * 16 + ln + dx][lg * 8];
#pragma unroll
            for (int gi = 0; gi < 3; ++gi) {
                if (gi < gn) {
                    s16x8 af = *(const s16x8*)&wfp[(size_t)(tap * 9 + g0 + gi) * 512];
#pragma unroll
                    for (int q = 0; q < 2; ++q)
                        acc[gi][q] = __builtin_amdgcn_mfma_f32_16x16x32_bf16(af, bf[q], acc[gi][q], 0, 0, 0);
                }
            }
        }
    }

    // epilogue: stores + per-channel partial stats
#pragma unroll
    for (int gi = 0; gi < 3; ++gi) {
        if (gi >= gn) continue;
        const int g = g0 + gi;
        float v[2][4];
#pragma unroll
        for (int q = 0; q < 2; ++q)
#pragma unroll
            for (int r = 0; r < 4; ++r)
                v[q][r] = acc[gi][q][r] + s_bias[g * 16 + lg * 4 + r];
#pragma unroll
        for (int q = 0; q < 2; ++q) {
            const int px  = half * 32 + q * 16 + ln;
            const int pxg = h * 4 + half * 2 + q;
            if (z == 0 && g == 8) {
                if (lg == 0) {
#pragma unroll
                    for (int r = 0; r < 2; ++r)
                        h_pre[((size_t)(n * 2 + r)) * HWSZ + h * 64 + px] = v[q][r];
                }
            } else {
                u16x4 vv;
#pragma unroll
                for (int r = 0; r < 4; ++r) vv[r] = f2bf(v[q][r]);
                int ks  = z * 4 + (g >> 1);
                int lgp = ((g & 1) * 2 + (lg >> 1)) & 3;
                size_t off = ((((size_t)(n * 256 + pxg) * 8 + ks) * 4 + lgp) * 128) + ln * 8 + (lg & 1) * 4;
                *(u16x4*)&m_frag[off] = vv;
            }
        }
#pragma unroll
        for (int r = 0; r < 4; ++r) {
            float s  = v[0][r] + v[1][r];
            float s2 = v[0][r] * v[0][r] + v[1][r] * v[1][r];
#pragma unroll
            for (int off = 1; off < 16; off <<= 1) {
                s  += __shfl_xor(s,  off, 64);
                s2 += __shfl_xor(s2, off, 64);
            }
            if (ln == 0) {
                s_ps[half][g * 16 + lg * 4 + r]  = s;
                s_ps2[half][g * 16 + lg * 4 + r] = s2;
            }
        }
    }
    __syncthreads();
    const int nch = z ? 128 : 130;
    if (tid < nch) {
        const int idx = z * 146 + tid;
        ps_s[(size_t)idx * 256 + hn]  = s_ps[0][tid] + s_ps[1][tid];
        ps_s2[(size_t)idx * 256 + hn] = s_ps2[0][tid] + s_ps2[1][tid];
    }
}

// ---------------------------------------------------------------------------
// K3: final BN stat reduction, one block per channel (258), 64 thr.
// ---------------------------------------------------------------------------
__global__ void __launch_bounds__(64)
bn_final2(const float* __restrict__ ps_s, const float* __restrict__ ps_s2,
          const float* __restrict__ mk_g, const float* __restrict__ mk_be,
          const float* __restrict__ fh_g, const float* __restrict__ fh_be,
          float* __restrict__ ab_m, float* __restrict__ ab_h)
{
    const int b = blockIdx.x;
    const int idx = (b < 256) ? ((b >> 7) * 146 + (b & 127)) : (128 + (b - 256));
    const int t = threadIdx.x;
    float S = 0.f, S2 = 0.f;
    const float* p1 = ps_s  + (size_t)idx * 256;
    const float* p2 = ps_s2 + (size_t)idx * 256;
    for (int i = t; i < 256; i += 64) { S += p1[i]; S2 += p2[i]; }
#pragma unroll
    for (int off = 32; off > 0; off >>= 1) {
        S += __shfl_down(S, off, 64); S2 += __shfl_down(S2, off, 64);
    }
    if (t == 0) {
        const float inv = 1.0f / (float)(N_B * HWSZ);
        float mu = S * inv;
        float var = S2 * inv - mu * mu;
        float r = rsqrtf(var + 1e-5f);
        if (b < 256) {
            float a = mk_g[b] * r;
            ab_m[2 * b] = a; ab_m[2 * b + 1] = mk_be[b] - mu * a;
        } else {
            int c = b - 256;
            float a = fh_g[c] * r;
            ab_h[2 * c] = a; ab_h[2 * c + 1] = fh_be[c] - mu * a;
        }
    }
}

// ---------------------------------------------------------------------------
// K4: flow conv2 only (BN+ReLU of m_frag fused into K5).
// ---------------------------------------------------------------------------
__global__ void __launch_bounds__(256)
flow_conv2(const float* __restrict__ hpre, const float* __restrict__ ab_h,
           const float* __restrict__ w2, const float* __restrict__ b2,
           float* __restrict__ flow8)
{
    int idx = blockIdx.x * 256 + threadIdx.x;
    int w = idx & 63, h = (idx >> 6) & 63, co = (idx >> 12) & 1, n = idx >> 13;
    float acc = b2[co];
#pragma unroll
    for (int ci = 0; ci < 2; ++ci) {
        float a = ab_h[2 * ci], b = ab_h[2 * ci + 1];
        const float* p = hpre + (size_t)(n * 2 + ci) * HWSZ;
        const float* wp = &w2[(co * 2 + ci) * 9];
#pragma unroll
        for (int dy = 0; dy < 3; ++dy)
#pragma unroll
            for (int dx = 0; dx < 3; ++dx) {
                int gy = h + dy - 1, gx = w + dx - 1;
                float v = 0.f;
                if ((unsigned)gy < 64u && (unsigned)gx < 64u)
                    v = fmaxf(a * p[gy * 64 + gx] + b, 0.f);
                acc += wp[dy * 3 + dx] * v;
            }
    }
    flow8[idx] = acc * 8.0f;
}

// ---------------------------------------------------------------------------
// K5: fused BN+ReLU + 1x1-conv GEMM + softmax + convex upsample (R17 skeleton).
// R19: B-frags read RAW from m_frag (pre-BN conv1 output) and transformed at
// load: y = f2bf(relu(a*x+b)) with c = ks*32+lg*8+j (bnrelu_flow's exact map)
// -> bit-identical to the old memory round-trip. s_ab = 2 KB LDS.
// Prefetch 2-deep (R15-proven neutral vs 4) to keep regs off the 128 cliff.
// 16 rows/block (4 passes), cross-pass prefetch, no-max softmax,
// double-buffered s_o, lane-contiguous stores. Grid 256.
// ---------------------------------------------------------------------------
__global__ void __launch_bounds__(1024, 4)
mask_combine_mfma(const unsigned short* __restrict__ m_frag,
                  const unsigned short* __restrict__ w2f,
                  const float* __restrict__ ab_m,
                  const float* __restrict__ mk_b2,
                  const float* __restrict__ flow8,
                  float* __restrict__ out)
{
    __shared__ unsigned short s_w[36864];       // 73,728 B
    __shared__ float s_o[2][8192];              // 65,536 B double-buffered
    __shared__ float s_fl[2][18][66];           // 9,504 B
    __shared__ float s_bias[9][16];             // 576 B
    __shared__ float s_ab[512];                 // 2,048 B  -> 151,392 B total

    const int id = blockIdx.x;
    const int uvt = id >> 4, r4 = id & 15;
    const int hg = r4 & 3, n = r4 >> 2;

    const int tid = threadIdx.x;
    const int wv = tid >> 6, lane = tid & 63;
    const int lg = lane >> 4, ln = lane & 15;
    const int row_l = wv >> 2, qq = wv & 3;
    const int w = qq * 16 + ln;

    // stage W tile (linear copy)
    {
        const u16x8* wsrc = (const u16x8*)(w2f + (size_t)uvt * 36864);
        u16x8* wdst = (u16x8*)s_w;
        for (int i = tid; i < 4608; i += 1024) wdst[i] = wsrc[i];
    }
    // stage flow rows hg*16-1 .. hg*16+16
    for (int i = tid; i < 2 * 18 * 66; i += 1024) {
        int c = i / 1188, rem = i - c * 1188, r = rem / 66, col = rem - r * 66;
        int gy = hg * 16 - 1 + r, gx = col - 1;
        float v = 0.f;
        if ((unsigned)gy < 64u && (unsigned)gx < 64u)
            v = flow8[((size_t)(n * 2 + c)) * HWSZ + gy * 64 + gx];
        s_fl[c][r][col] = v;
    }
    if (tid < 144) s_bias[tid >> 4][tid & 15] = 0.25f * mk_b2[(tid >> 4) * 256 + uvt * 16 + (tid & 15)];
    if (tid < 512) s_ab[tid] = ab_m[tid];
    __syncthreads();

    const unsigned short* wk0 = s_w + lg * 128 + ln * 8;
    const unsigned short* mb0 = m_frag + (size_t)(n * 256 + (hg * 16 + row_l) * 4 + qq) * 4096
                              + lg * 128 + ln * 8;
    const int cb0 = lg * 8;   // channel base offset within a ks-block

    // BN+ReLU transform on a raw B-frag (channels c = ks*32 + lg*8 + j)
    auto ldbn = [&](const unsigned short* p, int ks) -> s16x8 {
        u16x8 v = *(const u16x8*)p;
        u16x8 o;
        const int cb = ks * 32 + cb0;
#pragma unroll
        for (int j = 0; j < 8; ++j) {
            float a = s_ab[2 * (cb + j)], b = s_ab[2 * (cb + j) + 1];
            o[j] = f2bf(fmaxf(a * bf2f(v[j]) + b, 0.f));
        }
        union { u16x8 u; s16x8 s; } cvt; cvt.u = o;
        return cvt.s;
    };

    // prime 2-deep prefetch for pass 0
    s16x8 bq[2];
    bq[0] = ldbn(&mb0[0], 0);
    bq[1] = ldbn(&mb0[512], 1);

    for (int pass = 0; pass < 4; ++pass) {
        const unsigned short* mb = mb0 + (size_t)pass * 65536;   // +4 rows

        f32x4 acc[9];
#pragma unroll
        for (int k = 0; k < 9; ++k) acc[k] = (f32x4){0.f, 0.f, 0.f, 0.f};

#pragma unroll
        for (int ks = 0; ks < 8; ++ks) {
            const int d = ks & 1;
            const unsigned short* wk = wk0 + ks * 512;
#pragma unroll
            for (int k = 0; k < 9; ++k) {
                s16x8 af = *(const s16x8*)&wk[k * 4096];
                acc[k] = __builtin_amdgcn_mfma_f32_16x16x32_bf16(af, bq[d], acc[k], 0, 0, 0);
            }
            if (ks < 6) bq[d] = ldbn(&mb[(ks + 2) * 512], ks + 2);
        }
        // cross-pass prefetch: next pass's first 2 frags before epilogue VALU
        if (pass < 3) {
            bq[0] = ldbn(&mb[65536 + 0], 0);
            bq[1] = ldbn(&mb[65536 + 512], 1);
        }

        float* so = s_o[pass & 1];

        // epilogue: no-max softmax over 9 k + convex combine -> so
#pragma unroll
        for (int r = 0; r < 4; ++r) {
            const int vv = lg * 4 + r;
            float p[9], sum = 0.f;
#pragma unroll
            for (int k = 0; k < 9; ++k) {
                p[k] = __expf(acc[k][r] + s_bias[k][vv]);
                sum += p[k];
            }
            float inv = 1.0f / sum;
            float a0 = 0.f, a1 = 0.f;
#pragma unroll
            for (int k = 0; k < 9; ++k) {
                const int dy = k / 3, dx = k % 3;
                a0 += p[k] * s_fl[0][pass * 4 + row_l + dy][w + dx];
                a1 += p[k] * s_fl[1][pass * 4 + row_l + dy][w + dx];
            }
            so[(0 * 4 + row_l) * 1024 + w * 16 + vv] = a0 * inv;
            so[(1 * 4 + row_l) * 1024 + w * 16 + vv] = a1 * inv;
        }
        __syncthreads();

        // cooperative lane-contiguous store: 8 rows x 4KB, fully dense.
        for (int i = tid; i < 2048; i += 1024) {
            const int idx = i * 4;
            const int row = idx >> 10;       // 0..7: c = row>>2, rl = row&3
            const int col = idx & 1023;
            const int c = row >> 2, rl = row & 3;
            f32x4 v = *(const f32x4*)&so[idx];
            *(f32x4*)(out + ((size_t)(n * 2 + c) * 1024 +
                             (hg * 16 + pass * 4 + rl) * 16 + uvt) * 1024 + col) = v;
        }
        // next pass writes the other s_o buffer; barrier above protects reuse.
    }
}

// ---------------------------------------------------------------------------
extern "C" void kernel_launch(void* const* d_in, const int* in_sizes, int n_in,
                              void* d_out, int out_size, void* d_ws, size_t ws_size,
                              hipStream_t stream) {
    const float* img   = (const float*)d_in[0];
    const float* fh_w1 = (const float*)d_in[1];
    const float* fh_b1 = (const float*)d_in[2];
    const float* fh_g  = (const float*)d_in[3];
    const float* fh_be = (const float*)d_in[4];
    const float* fh_w2 = (const float*)d_in[5];
    const float* fh_b2 = (const float*)d_in[6];
    const float* mk_w1 = (const float*)d_in[7];
    const float* mk_b1 = (const float*)d_in[8];
    const float* mk_g  = (const float*)d_in[9];
    const float* mk_be = (const float*)d_in[10];
    const float* mk_w2 = (const float*)d_in[11];
    const float* mk_b2 = (const float*)d_in[12];
    float* out = (float*)d_out;

    char* p = (char*)d_ws;
    unsigned short* w2f    = (unsigned short*)p;  p += (size_t)1179648;
    unsigned short* w1f    = (unsigned short*)p;  p += (size_t)663552;
    unsigned short* m_frag = (unsigned short*)p;  p += (size_t)8388608;
    float* h_pre  = (float*)p;  p += (size_t)131072;
    float* flow8  = (float*)p;  p += (size_t)131072;
    float* ps_s   = (float*)p;  p += (size_t)280576;
    float* ps_s2  = (float*)p;  p += (size_t)280576;
    float* ab_m   = (float*)p;  p += 2048;
    float* ab_h   = (float*)p;  p += 64;

    prep_weights<<<2304, 256, 0, stream>>>(mk_w1, fh_w1, mk_w2, w1f, w2f);
    conv1_mfma<<<512, 512, 0, stream>>>(img, w1f, mk_b1, fh_b1, m_frag, h_pre, ps_s, ps_s2);
    bn_final2<<<258, 64, 0, stream>>>(ps_s, ps_s2, mk_g, mk_be, fh_g, fh_be, ab_m, ab_h);
    flow_conv2<<<128, 256, 0, stream>>>(h_pre, ab_h, fh_w2, fh_b2, flow8);
    mask_combine_mfma<<<256, 1024, 0, stream>>>(m_frag, w2f, ab_m, mk_b2, flow8, out);
}

// Round 20
// 81.221 us; speedup vs baseline: 1.0997x; 1.0997x over previous
//
#include <hip/hip_runtime.h>
#include <hip/hip_bf16.h>

#define N_B   4
#define C_IN  128
#define HWSZ  4096
#define C_M   256

typedef __attribute__((ext_vector_type(8))) short          s16x8;
typedef __attribute__((ext_vector_type(8))) unsigned short u16x8;
typedef __attribute__((ext_vector_type(4))) unsigned short u16x4;
typedef __attribute__((ext_vector_type(4))) float          f32x4;

__device__ __forceinline__ unsigned short f2bf(float f) {
    union { float f; unsigned u; } v; v.f = f;
    unsigned r = v.u + 0x7fffu + ((v.u >> 16) & 1u);   // RNE
    return (unsigned short)(r >> 16);
}
__device__ __forceinline__ float bf2f(unsigned short u) {
    union { unsigned u; float f; } v; v.u = ((unsigned)u) << 16; return v.f;
}

// ---------------------------------------------------------------------------
// K1: fused prep (R17 known-good). Blocks 0..255: img transpose to bf16
// (n,h,w,ci). Blocks 256..2559: fragment-ordered weights.
// ---------------------------------------------------------------------------
__global__ void __launch_bounds__(256)
prep_all(const float* __restrict__ img,
         const float* __restrict__ mk_w1, const float* __restrict__ fh_w1,
         const float* __restrict__ mk_w2,
         unsigned short* __restrict__ imgT,
         unsigned short* __restrict__ w1f, unsigned short* __restrict__ w2f)
{
    __shared__ float s[128][65];
    const int b = blockIdx.x;
    if (b < 256) {
        const int n = b >> 6, h = b & 63;
        const float* src = img + (size_t)n * C_IN * HWSZ + h * 64;
        for (int i = threadIdx.x; i < 128 * 64; i += 256) {
            int ci = i >> 6, w = i & 63;
            s[ci][w] = src[(size_t)ci * HWSZ + w];
        }
        __syncthreads();
        unsigned short* dst = imgT + ((size_t)(n * 64 + h) * 64) * 128;
        for (int i = threadIdx.x; i < 64 * 128; i += 256) {
            int w = i >> 7, ci = i & 127;
            dst[(size_t)w * 128 + ci] = f2bf(s[ci][w]);
        }
        return;
    }
    int i = (b - 256) * 256 + threadIdx.x;
    if (i < 2304 * 256) {
        int uvt = i / 36864;
        int r   = i - uvt * 36864;
        int k   = r / 4096;
        int r2  = r - k * 4096;
        int ks  = r2 >> 9;
        int lg  = (r2 >> 7) & 3;
        int ln  = (r2 >> 3) & 15;
        int j   = r2 & 7;
        w2f[i] = f2bf(0.25f * mk_w2[(size_t)(k * 256 + uvt * 16 + ln) * 256 + ks * 32 + lg * 8 + j]);
    }
    if (i < 2 * 4 * 9 * 9 * 512) {
        int z   = i / 165888;
        int r   = i - z * 165888;
        int cc  = r / 41472;
        int r2  = r - cc * 41472;
        int tap = r2 / 4608;
        int r3  = r2 - tap * 4608;
        int g   = r3 / 512;
        int r4  = r3 - g * 512;
        int lane = r4 >> 3, j = r4 & 7;
        int lg = lane >> 4, ln = lane & 15;
        int row = g * 16 + ln;
        int ci  = cc * 32 + lg * 8 + j;
        float w = 0.f;
        if (z == 0) {
            if (row < 128)      w = mk_w1[((size_t)row * C_IN + ci) * 9 + tap];
            else if (row < 130) w = fh_w1[((size_t)(row - 128) * C_IN + ci) * 9 + tap];
        } else {
            if (row < 128)      w = mk_w1[((size_t)(128 + row) * C_IN + ci) * 9 + tap];
        }
        w1f[i] = f2bf(w);
    }
}

// ---------------------------------------------------------------------------
// K2: conv1 implicit-GEMM 3x3 (R17 known-good: vector imgT staging).
// ---------------------------------------------------------------------------
__global__ void __launch_bounds__(512, 4)
conv1_mfma(const unsigned short* __restrict__ imgT,
           const unsigned short* __restrict__ w1f,
           const float* __restrict__ mk_b1, const float* __restrict__ fh_b1,
           unsigned short* __restrict__ m_frag, float* __restrict__ h_pre,
           float* __restrict__ ps_s, float* __restrict__ ps_s2)
{
    __shared__ unsigned short s_img[3][66][40];   // 15,840 B
    __shared__ float s_bias[144];
    __shared__ float s_ps[2][144], s_ps2[2][144];

    const int hw = blockIdx.x;
    const int xcd = hw & 7, slot = hw >> 3;
    const int lid = xcd * 64 + slot;
    const int n = lid >> 7, h = (lid >> 1) & 63, z = lid & 1;
    const int hn = n * 64 + h;

    const int tid = threadIdx.x;
    const int wv = tid >> 6, lane = tid & 63;
    const int lg = lane >> 4, ln = lane & 15;
    const int gq = wv >> 1, half = wv & 1;
    const int g0 = z ? (gq * 2) : ((int[4]){0, 3, 5, 7})[gq];
    const int gn = z ? 2 : ((int[4]){3, 2, 2, 2})[gq];

    if (tid < 144) {
        float b = 0.f;
        if (z == 0) {
            if (tid < 128)      b = mk_b1[tid];
            else if (tid < 130) b = fh_b1[tid - 128];
        } else if (tid < 128)   b = mk_b1[128 + tid];
        s_bias[tid] = b;
    }

    f32x4 acc[3][2];
#pragma unroll
    for (int g = 0; g < 3; ++g)
#pragma unroll
        for (int q = 0; q < 2; ++q) acc[g][q] = (f32x4){0.f, 0.f, 0.f, 0.f};

    for (int cc = 0; cc < 4; ++cc) {
        __syncthreads();
        for (int i = tid; i < 3 * 66 * 4; i += 512) {
            int r = i / 264;
            int rem = i - r * 264;
            int c = rem >> 2, un = rem & 3;
            int gy = h - 1 + r, gx = c - 1;
            u16x8 v = {0, 0, 0, 0, 0, 0, 0, 0};
            if ((unsigned)gy < 64u && (unsigned)gx < 64u)
                v = *(const u16x8*)&imgT[((size_t)((n * 64 + gy) * 64 + gx)) * 128 + cc * 32 + un * 8];
            *(u16x8*)&s_img[r][c][un * 8] = v;
        }
        __syncthreads();

        const unsigned short* wfp = w1f + (size_t)(z * 4 + cc) * 81 * 512 + lane * 8;
#pragma unroll
        for (int tap = 0; tap < 9; ++tap) {
            const int dy = tap / 3, dx = tap % 3;
            s16x8 bf[2];
#pragma unroll
            for (int q = 0; q < 2; ++q)
                bf[q] = *(const s16x8*)&s_img[dy][half * 32 + q * 16 + ln + dx][lg * 8];
#pragma unroll
            for (int gi = 0; gi < 3; ++gi) {
                if (gi < gn) {
                    s16x8 af = *(const s16x8*)&wfp[(size_t)(tap * 9 + g0 + gi) * 512];
#pragma unroll
                    for (int q = 0; q < 2; ++q)
                        acc[gi][q] = __builtin_amdgcn_mfma_f32_16x16x32_bf16(af, bf[q], acc[gi][q], 0, 0, 0);
                }
            }
        }
    }

    // epilogue: stores + per-channel partial stats
#pragma unroll
    for (int gi = 0; gi < 3; ++gi) {
        if (gi >= gn) continue;
        const int g = g0 + gi;
        float v[2][4];
#pragma unroll
        for (int q = 0; q < 2; ++q)
#pragma unroll
            for (int r = 0; r < 4; ++r)
                v[q][r] = acc[gi][q][r] + s_bias[g * 16 + lg * 4 + r];
#pragma unroll
        for (int q = 0; q < 2; ++q) {
            const int px  = half * 32 + q * 16 + ln;
            const int pxg = h * 4 + half * 2 + q;
            if (z == 0 && g == 8) {
                if (lg == 0) {
#pragma unroll
                    for (int r = 0; r < 2; ++r)
                        h_pre[((size_t)(n * 2 + r)) * HWSZ + h * 64 + px] = v[q][r];
                }
            } else {
                u16x4 vv;
#pragma unroll
                for (int r = 0; r < 4; ++r) vv[r] = f2bf(v[q][r]);
                int ks  = z * 4 + (g >> 1);
                int lgp = ((g & 1) * 2 + (lg >> 1)) & 3;
                size_t off = ((((size_t)(n * 256 + pxg) * 8 + ks) * 4 + lgp) * 128) + ln * 8 + (lg & 1) * 4;
                *(u16x4*)&m_frag[off] = vv;
            }
        }
#pragma unroll
        for (int r = 0; r < 4; ++r) {
            float s  = v[0][r] + v[1][r];
            float s2 = v[0][r] * v[0][r] + v[1][r] * v[1][r];
#pragma unroll
            for (int off = 1; off < 16; off <<= 1) {
                s  += __shfl_xor(s,  off, 64);
                s2 += __shfl_xor(s2, off, 64);
            }
            if (ln == 0) {
                s_ps[half][g * 16 + lg * 4 + r]  = s;
                s_ps2[half][g * 16 + lg * 4 + r] = s2;
            }
        }
    }
    __syncthreads();
    const int nch = z ? 128 : 130;
    if (tid < nch) {
        const int idx = z * 146 + tid;
        ps_s[(size_t)idx * 256 + hn]  = s_ps[0][tid] + s_ps[1][tid];
        ps_s2[(size_t)idx * 256 + hn] = s_ps2[0][tid] + s_ps2[1][tid];
    }
}

// ---------------------------------------------------------------------------
// K3: final BN stat reduction, one block per channel (258), 64 thr.
// ---------------------------------------------------------------------------
__global__ void __launch_bounds__(64)
bn_final2(const float* __restrict__ ps_s, const float* __restrict__ ps_s2,
          const float* __restrict__ mk_g, const float* __restrict__ mk_be,
          const float* __restrict__ fh_g, const float* __restrict__ fh_be,
          float* __restrict__ ab_m, float* __restrict__ ab_h)
{
    const int b = blockIdx.x;
    const int idx = (b < 256) ? ((b >> 7) * 146 + (b & 127)) : (128 + (b - 256));
    const int t = threadIdx.x;
    float S = 0.f, S2 = 0.f;
    const float* p1 = ps_s  + (size_t)idx * 256;
    const float* p2 = ps_s2 + (size_t)idx * 256;
    for (int i = t; i < 256; i += 64) { S += p1[i]; S2 += p2[i]; }
#pragma unroll
    for (int off = 32; off > 0; off >>= 1) {
        S += __shfl_down(S, off, 64); S2 += __shfl_down(S2, off, 64);
    }
    if (t == 0) {
        const float inv = 1.0f / (float)(N_B * HWSZ);
        float mu = S * inv;
        float var = S2 * inv - mu * mu;
        float r = rsqrtf(var + 1e-5f);
        if (b < 256) {
            float a = mk_g[b] * r;
            ab_m[2 * b] = a; ab_m[2 * b + 1] = mk_be[b] - mu * a;
        } else {
            int c = b - 256;
            float a = fh_g[c] * r;
            ab_h[2 * c] = a; ab_h[2 * c + 1] = fh_be[c] - mu * a;
        }
    }
}

// ---------------------------------------------------------------------------
// K4: flow conv2 only (BN+ReLU of m_frag fused into K5).
// ---------------------------------------------------------------------------
__global__ void __launch_bounds__(256)
flow_conv2(const float* __restrict__ hpre, const float* __restrict__ ab_h,
           const float* __restrict__ w2, const float* __restrict__ b2,
           float* __restrict__ flow8)
{
    int idx = blockIdx.x * 256 + threadIdx.x;
    int w = idx & 63, h = (idx >> 6) & 63, co = (idx >> 12) & 1, n = idx >> 13;
    float acc = b2[co];
#pragma unroll
    for (int ci = 0; ci < 2; ++ci) {
        float a = ab_h[2 * ci], b = ab_h[2 * ci + 1];
        const float* p = hpre + (size_t)(n * 2 + ci) * HWSZ;
        const float* wp = &w2[(co * 2 + ci) * 9];
#pragma unroll
        for (int dy = 0; dy < 3; ++dy)
#pragma unroll
            for (int dx = 0; dx < 3; ++dx) {
                int gy = h + dy - 1, gx = w + dx - 1;
                float v = 0.f;
                if ((unsigned)gy < 64u && (unsigned)gx < 64u)
                    v = fmaxf(a * p[gy * 64 + gx] + b, 0.f);
                acc += wp[dy * 3 + dx] * v;
            }
    }
    flow8[idx] = acc * 8.0f;
}

// ---------------------------------------------------------------------------
// K5: fused BN+ReLU + 1x1-conv GEMM + softmax + convex upsample
// (R19 version, passed with absmax 0.0078). B-frags transformed at load:
// y = f2bf(relu(a*x+b)), c = ks*32+lg*8+j. 2-deep prefetch, 4 passes,
// cross-pass prefetch, no-max softmax, dbuf s_o, lane-contiguous stores.
// ---------------------------------------------------------------------------
__global__ void __launch_bounds__(1024, 4)
mask_combine_mfma(const unsigned short* __restrict__ m_frag,
                  const unsigned short* __restrict__ w2f,
                  const float* __restrict__ ab_m,
                  const float* __restrict__ mk_b2,
                  const float* __restrict__ flow8,
                  float* __restrict__ out)
{
    __shared__ unsigned short s_w[36864];       // 73,728 B
    __shared__ float s_o[2][8192];              // 65,536 B double-buffered
    __shared__ float s_fl[2][18][66];           // 9,504 B
    __shared__ float s_bias[9][16];             // 576 B
    __shared__ float s_ab[512];                 // 2,048 B

    const int id = blockIdx.x;
    const int uvt = id >> 4, r4 = id & 15;
    const int hg = r4 & 3, n = r4 >> 2;

    const int tid = threadIdx.x;
    const int wv = tid >> 6, lane = tid & 63;
    const int lg = lane >> 4, ln = lane & 15;
    const int row_l = wv >> 2, qq = wv & 3;
    const int w = qq * 16 + ln;

    {
        const u16x8* wsrc = (const u16x8*)(w2f + (size_t)uvt * 36864);
        u16x8* wdst = (u16x8*)s_w;
        for (int i = tid; i < 4608; i += 1024) wdst[i] = wsrc[i];
    }
    for (int i = tid; i < 2 * 18 * 66; i += 1024) {
        int c = i / 1188, rem = i - c * 1188, r = rem / 66, col = rem - r * 66;
        int gy = hg * 16 - 1 + r, gx = col - 1;
        float v = 0.f;
        if ((unsigned)gy < 64u && (unsigned)gx < 64u)
            v = flow8[((size_t)(n * 2 + c)) * HWSZ + gy * 64 + gx];
        s_fl[c][r][col] = v;
    }
    if (tid < 144) s_bias[tid >> 4][tid & 15] = 0.25f * mk_b2[(tid >> 4) * 256 + uvt * 16 + (tid & 15)];
    if (tid < 512) s_ab[tid] = ab_m[tid];
    __syncthreads();

    const unsigned short* wk0 = s_w + lg * 128 + ln * 8;
    const unsigned short* mb0 = m_frag + (size_t)(n * 256 + (hg * 16 + row_l) * 4 + qq) * 4096
                              + lg * 128 + ln * 8;
    const int cb0 = lg * 8;

    auto ldbn = [&](const unsigned short* p, int ks) -> s16x8 {
        u16x8 v = *(const u16x8*)p;
        u16x8 o;
        const int cb = ks * 32 + cb0;
#pragma unroll
        for (int j = 0; j < 8; ++j) {
            float a = s_ab[2 * (cb + j)], b = s_ab[2 * (cb + j) + 1];
            o[j] = f2bf(fmaxf(a * bf2f(v[j]) + b, 0.f));
        }
        union { u16x8 u; s16x8 s; } cvt; cvt.u = o;
        return cvt.s;
    };

    s16x8 bq[2];
    bq[0] = ldbn(&mb0[0], 0);
    bq[1] = ldbn(&mb0[512], 1);

    for (int pass = 0; pass < 4; ++pass) {
        const unsigned short* mb = mb0 + (size_t)pass * 65536;   // +4 rows

        f32x4 acc[9];
#pragma unroll
        for (int k = 0; k < 9; ++k) acc[k] = (f32x4){0.f, 0.f, 0.f, 0.f};

#pragma unroll
        for (int ks = 0; ks < 8; ++ks) {
            const int d = ks & 1;
            const unsigned short* wk = wk0 + ks * 512;
#pragma unroll
            for (int k = 0; k < 9; ++k) {
                s16x8 af = *(const s16x8*)&wk[k * 4096];
                acc[k] = __builtin_amdgcn_mfma_f32_16x16x32_bf16(af, bq[d], acc[k], 0, 0, 0);
            }
            if (ks < 6) bq[d] = ldbn(&mb[(ks + 2) * 512], ks + 2);
        }
        if (pass < 3) {
            bq[0] = ldbn(&mb[65536 + 0], 0);
            bq[1] = ldbn(&mb[65536 + 512], 1);
        }

        float* so = s_o[pass & 1];

#pragma unroll
        for (int r = 0; r < 4; ++r) {
            const int vv = lg * 4 + r;
            float p[9], sum = 0.f;
#pragma unroll
            for (int k = 0; k < 9; ++k) {
                p[k] = __expf(acc[k][r] + s_bias[k][vv]);
                sum += p[k];
            }
            float inv = 1.0f / sum;
            float a0 = 0.f, a1 = 0.f;
#pragma unroll
            for (int k = 0; k < 9; ++k) {
                const int dy = k / 3, dx = k % 3;
                a0 += p[k] * s_fl[0][pass * 4 + row_l + dy][w + dx];
                a1 += p[k] * s_fl[1][pass * 4 + row_l + dy][w + dx];
            }
            so[(0 * 4 + row_l) * 1024 + w * 16 + vv] = a0 * inv;
            so[(1 * 4 + row_l) * 1024 + w * 16 + vv] = a1 * inv;
        }
        __syncthreads();

        for (int i = tid; i < 2048; i += 1024) {
            const int idx = i * 4;
            const int row = idx >> 10;
            const int col = idx & 1023;
            const int c = row >> 2, rl = row & 3;
            f32x4 v = *(const f32x4*)&so[idx];
            *(f32x4*)(out + ((size_t)(n * 2 + c) * 1024 +
                             (hg * 16 + pass * 4 + rl) * 16 + uvt) * 1024 + col) = v;
        }
    }
}

// ---------------------------------------------------------------------------
extern "C" void kernel_launch(void* const* d_in, const int* in_sizes, int n_in,
                              void* d_out, int out_size, void* d_ws, size_t ws_size,
                              hipStream_t stream) {
    const float* img   = (const float*)d_in[0];
    const float* fh_w1 = (const float*)d_in[1];
    const float* fh_b1 = (const float*)d_in[2];
    const float* fh_g  = (const float*)d_in[3];
    const float* fh_be = (const float*)d_in[4];
    const float* fh_w2 = (const float*)d_in[5];
    const float* fh_b2 = (const float*)d_in[6];
    const float* mk_w1 = (const float*)d_in[7];
    const float* mk_b1 = (const float*)d_in[8];
    const float* mk_g  = (const float*)d_in[9];
    const float* mk_be = (const float*)d_in[10];
    const float* mk_w2 = (const float*)d_in[11];
    const float* mk_b2 = (const float*)d_in[12];
    float* out = (float*)d_out;

    char* p = (char*)d_ws;
    unsigned short* w2f    = (unsigned short*)p;  p += (size_t)1179648;
    unsigned short* w1f    = (unsigned short*)p;  p += (size_t)663552;
    unsigned short* imgT   = (unsigned short*)p;  p += (size_t)4194304;
    unsigned short* m_frag = (unsigned short*)p;  p += (size_t)8388608;
    float* h_pre  = (float*)p;  p += (size_t)131072;
    float* flow8  = (float*)p;  p += (size_t)131072;
    float* ps_s   = (float*)p;  p += (size_t)280576;
    float* ps_s2  = (float*)p;  p += (size_t)280576;
    float* ab_m   = (float*)p;  p += 2048;
    float* ab_h   = (float*)p;  p += 64;

    prep_all<<<2560, 256, 0, stream>>>(img, mk_w1, fh_w1, mk_w2, imgT, w1f, w2f);
    conv1_mfma<<<512, 512, 0, stream>>>(imgT, w1f, mk_b1, fh_b1, m_frag, h_pre, ps_s, ps_s2);
    bn_final2<<<258, 64, 0, stream>>>(ps_s, ps_s2, mk_g, mk_be, fh_g, fh_be, ab_m, ab_h);
    flow_conv2<<<128, 256, 0, stream>>>(h_pre, ab_h, fh_w2, fh_b2, flow8);
    mask_combine_mfma<<<256, 1024, 0, stream>>>(m_frag, w2f, ab_m, mk_b2, flow8, out);
}

// Round 21
// 77.110 us; speedup vs baseline: 1.1583x; 1.0533x over previous
//
#include <hip/hip_runtime.h>
#include <hip/hip_bf16.h>

#define N_B   4
#define C_IN  128
#define HWSZ  4096
#define C_M   256

typedef __attribute__((ext_vector_type(8))) short          s16x8;
typedef __attribute__((ext_vector_type(8))) unsigned short u16x8;
typedef __attribute__((ext_vector_type(4))) unsigned short u16x4;
typedef __attribute__((ext_vector_type(4))) float          f32x4;

__device__ __forceinline__ unsigned short f2bf(float f) {
    union { float f; unsigned u; } v; v.f = f;
    unsigned r = v.u + 0x7fffu + ((v.u >> 16) & 1u);   // RNE
    return (unsigned short)(r >> 16);
}
__device__ __forceinline__ float bf2f(unsigned short u) {
    union { unsigned u; float f; } v; v.u = ((unsigned)u) << 16; return v.f;
}

// ---------------------------------------------------------------------------
// K1: fused prep. Blocks 0..255: img transpose (n,ci,h,w)->bf16 (n,h,w,ci).
// Blocks 256..2559: fragment-ordered weights.
// ---------------------------------------------------------------------------
__global__ void __launch_bounds__(256)
prep_all(const float* __restrict__ img,
         const float* __restrict__ mk_w1, const float* __restrict__ fh_w1,
         const float* __restrict__ mk_w2,
         unsigned short* __restrict__ imgT,
         unsigned short* __restrict__ w1f, unsigned short* __restrict__ w2f)
{
    __shared__ float s[128][65];
    const int b = blockIdx.x;
    if (b < 256) {
        const int n = b >> 6, h = b & 63;
        const float* src = img + (size_t)n * C_IN * HWSZ + h * 64;
        for (int i = threadIdx.x; i < 128 * 64; i += 256) {
            int ci = i >> 6, w = i & 63;
            s[ci][w] = src[(size_t)ci * HWSZ + w];
        }
        __syncthreads();
        unsigned short* dst = imgT + ((size_t)(n * 64 + h) * 64) * 128;
        for (int i = threadIdx.x; i < 64 * 128; i += 256) {
            int w = i >> 7, ci = i & 127;
            dst[(size_t)w * 128 + ci] = f2bf(s[ci][w]);
        }
        return;
    }
    int i = (b - 256) * 256 + threadIdx.x;
    if (i < 2304 * 256) {
        int uvt = i / 36864;
        int r   = i - uvt * 36864;
        int k   = r / 4096;
        int r2  = r - k * 4096;
        int ks  = r2 >> 9;
        int lg  = (r2 >> 7) & 3;
        int ln  = (r2 >> 3) & 15;
        int j   = r2 & 7;
        w2f[i] = f2bf(0.25f * mk_w2[(size_t)(k * 256 + uvt * 16 + ln) * 256 + ks * 32 + lg * 8 + j]);
    }
    if (i < 2 * 4 * 9 * 9 * 512) {
        int z   = i / 165888;
        int r   = i - z * 165888;
        int cc  = r / 41472;
        int r2  = r - cc * 41472;
        int tap = r2 / 4608;
        int r3  = r2 - tap * 4608;
        int g   = r3 / 512;
        int r4  = r3 - g * 512;
        int lane = r4 >> 3, j = r4 & 7;
        int lg = lane >> 4, ln = lane & 15;
        int row = g * 16 + ln;
        int ci  = cc * 32 + lg * 8 + j;
        float w = 0.f;
        if (z == 0) {
            if (row < 128)      w = mk_w1[((size_t)row * C_IN + ci) * 9 + tap];
            else if (row < 130) w = fh_w1[((size_t)(row - 128) * C_IN + ci) * 9 + tap];
        } else {
            if (row < 128)      w = mk_w1[((size_t)(128 + row) * C_IN + ci) * 9 + tap];
        }
        w1f[i] = f2bf(w);
    }
}

// ---------------------------------------------------------------------------
// K2: conv1 implicit-GEMM 3x3 (known-good).
// ---------------------------------------------------------------------------
__global__ void __launch_bounds__(512, 4)
conv1_mfma(const unsigned short* __restrict__ imgT,
           const unsigned short* __restrict__ w1f,
           const float* __restrict__ mk_b1, const float* __restrict__ fh_b1,
           unsigned short* __restrict__ m_frag, float* __restrict__ h_pre,
           float* __restrict__ ps_s, float* __restrict__ ps_s2)
{
    __shared__ unsigned short s_img[3][66][40];   // 15,840 B
    __shared__ float s_bias[144];
    __shared__ float s_ps[2][144], s_ps2[2][144];

    const int hw = blockIdx.x;
    const int xcd = hw & 7, slot = hw >> 3;
    const int lid = xcd * 64 + slot;
    const int n = lid >> 7, h = (lid >> 1) & 63, z = lid & 1;
    const int hn = n * 64 + h;

    const int tid = threadIdx.x;
    const int wv = tid >> 6, lane = tid & 63;
    const int lg = lane >> 4, ln = lane & 15;
    const int gq = wv >> 1, half = wv & 1;
    const int g0 = z ? (gq * 2) : ((int[4]){0, 3, 5, 7})[gq];
    const int gn = z ? 2 : ((int[4]){3, 2, 2, 2})[gq];

    if (tid < 144) {
        float b = 0.f;
        if (z == 0) {
            if (tid < 128)      b = mk_b1[tid];
            else if (tid < 130) b = fh_b1[tid - 128];
        } else if (tid < 128)   b = mk_b1[128 + tid];
        s_bias[tid] = b;
    }

    f32x4 acc[3][2];
#pragma unroll
    for (int g = 0; g < 3; ++g)
#pragma unroll
        for (int q = 0; q < 2; ++q) acc[g][q] = (f32x4){0.f, 0.f, 0.f, 0.f};

    for (int cc = 0; cc < 4; ++cc) {
        __syncthreads();
        for (int i = tid; i < 3 * 66 * 4; i += 512) {
            int r = i / 264;
            int rem = i - r * 264;
            int c = rem >> 2, un = rem & 3;
            int gy = h - 1 + r, gx = c - 1;
            u16x8 v = {0, 0, 0, 0, 0, 0, 0, 0};
            if ((unsigned)gy < 64u && (unsigned)gx < 64u)
                v = *(const u16x8*)&imgT[((size_t)((n * 64 + gy) * 64 + gx)) * 128 + cc * 32 + un * 8];
            *(u16x8*)&s_img[r][c][un * 8] = v;
        }
        __syncthreads();

        const unsigned short* wfp = w1f + (size_t)(z * 4 + cc) * 81 * 512 + lane * 8;
#pragma unroll
        for (int tap = 0; tap < 9; ++tap) {
            const int dy = tap / 3, dx = tap % 3;
            s16x8 bf[2];
#pragma unroll
            for (int q = 0; q < 2; ++q)
                bf[q] = *(const s16x8*)&s_img[dy][half * 32 + q * 16 + ln + dx][lg * 8];
#pragma unroll
            for (int gi = 0; gi < 3; ++gi) {
                if (gi < gn) {
                    s16x8 af = *(const s16x8*)&wfp[(size_t)(tap * 9 + g0 + gi) * 512];
#pragma unroll
                    for (int q = 0; q < 2; ++q)
                        acc[gi][q] = __builtin_amdgcn_mfma_f32_16x16x32_bf16(af, bf[q], acc[gi][q], 0, 0, 0);
                }
            }
        }
    }

    // epilogue: stores + per-channel partial stats
#pragma unroll
    for (int gi = 0; gi < 3; ++gi) {
        if (gi >= gn) continue;
        const int g = g0 + gi;
        float v[2][4];
#pragma unroll
        for (int q = 0; q < 2; ++q)
#pragma unroll
            for (int r = 0; r < 4; ++r)
                v[q][r] = acc[gi][q][r] + s_bias[g * 16 + lg * 4 + r];
#pragma unroll
        for (int q = 0; q < 2; ++q) {
            const int px  = half * 32 + q * 16 + ln;
            const int pxg = h * 4 + half * 2 + q;
            if (z == 0 && g == 8) {
                if (lg == 0) {
#pragma unroll
                    for (int r = 0; r < 2; ++r)
                        h_pre[((size_t)(n * 2 + r)) * HWSZ + h * 64 + px] = v[q][r];
                }
            } else {
                u16x4 vv;
#pragma unroll
                for (int r = 0; r < 4; ++r) vv[r] = f2bf(v[q][r]);
                int ks  = z * 4 + (g >> 1);
                int lgp = ((g & 1) * 2 + (lg >> 1)) & 3;
                size_t off = ((((size_t)(n * 256 + pxg) * 8 + ks) * 4 + lgp) * 128) + ln * 8 + (lg & 1) * 4;
                *(u16x4*)&m_frag[off] = vv;
            }
        }
#pragma unroll
        for (int r = 0; r < 4; ++r) {
            float s  = v[0][r] + v[1][r];
            float s2 = v[0][r] * v[0][r] + v[1][r] * v[1][r];
#pragma unroll
            for (int off = 1; off < 16; off <<= 1) {
                s  += __shfl_xor(s,  off, 64);
                s2 += __shfl_xor(s2, off, 64);
            }
            if (ln == 0) {
                s_ps[half][g * 16 + lg * 4 + r]  = s;
                s_ps2[half][g * 16 + lg * 4 + r] = s2;
            }
        }
    }
    __syncthreads();
    const int nch = z ? 128 : 130;
    if (tid < nch) {
        const int idx = z * 146 + tid;
        ps_s[(size_t)idx * 256 + hn]  = s_ps[0][tid] + s_ps[1][tid];
        ps_s2[(size_t)idx * 256 + hn] = s_ps2[0][tid] + s_ps2[1][tid];
    }
}

// ---------------------------------------------------------------------------
// K3: final BN stat reduction, one block per channel (258), 64 thr.
// ---------------------------------------------------------------------------
__global__ void __launch_bounds__(64)
bn_final2(const float* __restrict__ ps_s, const float* __restrict__ ps_s2,
          const float* __restrict__ mk_g, const float* __restrict__ mk_be,
          const float* __restrict__ fh_g, const float* __restrict__ fh_be,
          float* __restrict__ ab_m, float* __restrict__ ab_h)
{
    const int b = blockIdx.x;
    const int idx = (b < 256) ? ((b >> 7) * 146 + (b & 127)) : (128 + (b - 256));
    const int t = threadIdx.x;
    float S = 0.f, S2 = 0.f;
    const float* p1 = ps_s  + (size_t)idx * 256;
    const float* p2 = ps_s2 + (size_t)idx * 256;
    for (int i = t; i < 256; i += 64) { S += p1[i]; S2 += p2[i]; }
#pragma unroll
    for (int off = 32; off > 0; off >>= 1) {
        S += __shfl_down(S, off, 64); S2 += __shfl_down(S2, off, 64);
    }
    if (t == 0) {
        const float inv = 1.0f / (float)(N_B * HWSZ);
        float mu = S * inv;
        float var = S2 * inv - mu * mu;
        float r = rsqrtf(var + 1e-5f);
        if (b < 256) {
            float a = mk_g[b] * r;
            ab_m[2 * b] = a; ab_m[2 * b + 1] = mk_be[b] - mu * a;
        } else {
            int c = b - 256;
            float a = fh_g[c] * r;
            ab_h[2 * c] = a; ab_h[2 * c + 1] = fh_be[c] - mu * a;
        }
    }
}

// ---------------------------------------------------------------------------
// K4: blocks 0..2047 in-place BN+ReLU on m_frag; blocks 2048..2175 flow conv2.
// ---------------------------------------------------------------------------
__global__ void __launch_bounds__(256)
bnrelu_flow(unsigned short* __restrict__ m_frag, const float* __restrict__ ab,
            const float* __restrict__ hpre, const float* __restrict__ ab_h,
            const float* __restrict__ w2, const float* __restrict__ b2,
            float* __restrict__ flow8)
{
    __shared__ float s_ab[512];
    const int t = threadIdx.x;
    if (blockIdx.x < 2048) {
        s_ab[t] = ab[t]; s_ab[256 + t] = ab[256 + t];
        __syncthreads();
        const unsigned u = blockIdx.x * 256 + t;
        const int lg = (u >> 4) & 3, ks = (u >> 7) & 7;
        const int cb = ks * 32 + lg * 8;
        u16x8 v = *(const u16x8*)&m_frag[(size_t)u * 8];
        u16x8 o;
#pragma unroll
        for (int j = 0; j < 8; ++j) {
            float a = s_ab[2 * (cb + j)], b = s_ab[2 * (cb + j) + 1];
            o[j] = f2bf(fmaxf(a * bf2f(v[j]) + b, 0.f));
        }
        *(u16x8*)&m_frag[(size_t)u * 8] = o;
        return;
    }
    int idx = (blockIdx.x - 2048) * 256 + t;
    int w = idx & 63, h = (idx >> 6) & 63, co = (idx >> 12) & 1, n = idx >> 13;
    float acc = b2[co];
#pragma unroll
    for (int ci = 0; ci < 2; ++ci) {
        float a = ab_h[2 * ci], b = ab_h[2 * ci + 1];
        const float* p = hpre + (size_t)(n * 2 + ci) * HWSZ;
        const float* wp = &w2[(co * 2 + ci) * 9];
#pragma unroll
        for (int dy = 0; dy < 3; ++dy)
#pragma unroll
            for (int dx = 0; dx < 3; ++dx) {
                int gy = h + dy - 1, gx = w + dx - 1;
                float v = 0.f;
                if ((unsigned)gy < 64u && (unsigned)gx < 64u)
                    v = fmaxf(a * p[gy * 64 + gx] + b, 0.f);
                acc += wp[dy * 3 + dx] * v;
            }
    }
    flow8[idx] = acc * 8.0f;
}

// ---------------------------------------------------------------------------
// K5: fused 1x1-conv GEMM + bias + softmax(9) + convex upsample (R17 best).
// 16 rows/block (4 passes), cross-pass 4-deep prefetch, no-max softmax,
// double-buffered s_o, lane-contiguous stores. Grid 256.
// ---------------------------------------------------------------------------
__global__ void __launch_bounds__(1024, 4)
mask_combine_mfma(const unsigned short* __restrict__ m_frag,
                  const unsigned short* __restrict__ w2f,
                  const float* __restrict__ mk_b2,
                  const float* __restrict__ flow8,
                  float* __restrict__ out)
{
    __shared__ unsigned short s_w[36864];       // 73,728 B
    __shared__ float s_o[2][8192];              // 65,536 B double-buffered
    __shared__ float s_fl[2][18][66];           // 9,504 B
    __shared__ float s_bias[9][16];             // 576 B

    const int id = blockIdx.x;
    const int uvt = id >> 4, r4 = id & 15;
    const int hg = r4 & 3, n = r4 >> 2;

    const int tid = threadIdx.x;
    const int wv = tid >> 6, lane = tid & 63;
    const int lg = lane >> 4, ln = lane & 15;
    const int row_l = wv >> 2, qq = wv & 3;
    const int w = qq * 16 + ln;

    {
        const u16x8* wsrc = (const u16x8*)(w2f + (size_t)uvt * 36864);
        u16x8* wdst = (u16x8*)s_w;
        for (int i = tid; i < 4608; i += 1024) wdst[i] = wsrc[i];
    }
    for (int i = tid; i < 2 * 18 * 66; i += 1024) {
        int c = i / 1188, rem = i - c * 1188, r = rem / 66, col = rem - r * 66;
        int gy = hg * 16 - 1 + r, gx = col - 1;
        float v = 0.f;
        if ((unsigned)gy < 64u && (unsigned)gx < 64u)
            v = flow8[((size_t)(n * 2 + c)) * HWSZ + gy * 64 + gx];
        s_fl[c][r][col] = v;
    }
    if (tid < 144) s_bias[tid >> 4][tid & 15] = 0.25f * mk_b2[(tid >> 4) * 256 + uvt * 16 + (tid & 15)];
    __syncthreads();

    const unsigned short* wk0 = s_w + lg * 128 + ln * 8;
    const unsigned short* mb0 = m_frag + (size_t)(n * 256 + (hg * 16 + row_l) * 4 + qq) * 4096
                              + lg * 128 + ln * 8;

    s16x8 bq[4];
#pragma unroll
    for (int d = 0; d < 4; ++d) bq[d] = *(const s16x8*)&mb0[d * 512];

    for (int pass = 0; pass < 4; ++pass) {
        const unsigned short* mb = mb0 + (size_t)pass * 65536;   // +4 rows

        f32x4 acc[9];
#pragma unroll
        for (int k = 0; k < 9; ++k) acc[k] = (f32x4){0.f, 0.f, 0.f, 0.f};

#pragma unroll
        for (int ks = 0; ks < 8; ++ks) {
            const int d = ks & 3;
            const unsigned short* wk = wk0 + ks * 512;
#pragma unroll
            for (int k = 0; k < 9; ++k) {
                s16x8 af = *(const s16x8*)&wk[k * 4096];
                acc[k] = __builtin_amdgcn_mfma_f32_16x16x32_bf16(af, bq[d], acc[k], 0, 0, 0);
            }
            if (ks < 4) bq[d] = *(const s16x8*)&mb[(ks + 4) * 512];
        }
        if (pass < 3) {
#pragma unroll
            for (int d = 0; d < 4; ++d)
                bq[d] = *(const s16x8*)&mb[65536 + d * 512];
        }

        float* so = s_o[pass & 1];

#pragma unroll
        for (int r = 0; r < 4; ++r) {
            const int vv = lg * 4 + r;
            float p[9], sum = 0.f;
#pragma unroll
            for (int k = 0; k < 9; ++k) {
                p[k] = __expf(acc[k][r] + s_bias[k][vv]);
                sum += p[k];
            }
            float inv = 1.0f / sum;
            float a0 = 0.f, a1 = 0.f;
#pragma unroll
            for (int k = 0; k < 9; ++k) {
                const int dy = k / 3, dx = k % 3;
                a0 += p[k] * s_fl[0][pass * 4 + row_l + dy][w + dx];
                a1 += p[k] * s_fl[1][pass * 4 + row_l + dy][w + dx];
            }
            so[(0 * 4 + row_l) * 1024 + w * 16 + vv] = a0 * inv;
            so[(1 * 4 + row_l) * 1024 + w * 16 + vv] = a1 * inv;
        }
        __syncthreads();

        for (int i = tid; i < 2048; i += 1024) {
            const int idx = i * 4;
            const int row = idx >> 10;
            const int col = idx & 1023;
            const int c = row >> 2, rl = row & 3;
            f32x4 v = *(const f32x4*)&so[idx];
            *(f32x4*)(out + ((size_t)(n * 2 + c) * 1024 +
                             (hg * 16 + pass * 4 + rl) * 16 + uvt) * 1024 + col) = v;
        }
    }
}

// ---------------------------------------------------------------------------
extern "C" void kernel_launch(void* const* d_in, const int* in_sizes, int n_in,
                              void* d_out, int out_size, void* d_ws, size_t ws_size,
                              hipStream_t stream) {
    const float* img   = (const float*)d_in[0];
    const float* fh_w1 = (const float*)d_in[1];
    const float* fh_b1 = (const float*)d_in[2];
    const float* fh_g  = (const float*)d_in[3];
    const float* fh_be = (const float*)d_in[4];
    const float* fh_w2 = (const float*)d_in[5];
    const float* fh_b2 = (const float*)d_in[6];
    const float* mk_w1 = (const float*)d_in[7];
    const float* mk_b1 = (const float*)d_in[8];
    const float* mk_g  = (const float*)d_in[9];
    const float* mk_be = (const float*)d_in[10];
    const float* mk_w2 = (const float*)d_in[11];
    const float* mk_b2 = (const float*)d_in[12];
    float* out = (float*)d_out;

    char* p = (char*)d_ws;
    unsigned short* w2f    = (unsigned short*)p;  p += (size_t)1179648;
    unsigned short* w1f    = (unsigned short*)p;  p += (size_t)663552;
    unsigned short* imgT   = (unsigned short*)p;  p += (size_t)4194304;
    unsigned short* m_frag = (unsigned short*)p;  p += (size_t)8388608;
    float* h_pre  = (float*)p;  p += (size_t)131072;
    float* flow8  = (float*)p;  p += (size_t)131072;
    float* ps_s   = (float*)p;  p += (size_t)280576;
    float* ps_s2  = (float*)p;  p += (size_t)280576;
    float* ab_m   = (float*)p;  p += 2048;
    float* ab_h   = (float*)p;  p += 64;

    prep_all<<<2560, 256, 0, stream>>>(img, mk_w1, fh_w1, mk_w2, imgT, w1f, w2f);
    conv1_mfma<<<512, 512, 0, stream>>>(imgT, w1f, mk_b1, fh_b1, m_frag, h_pre, ps_s, ps_s2);
    bn_final2<<<258, 64, 0, stream>>>(ps_s, ps_s2, mk_g, mk_be, fh_g, fh_be, ab_m, ab_h);
    bnrelu_flow<<<2176, 256, 0, stream>>>(m_frag, ab_m, h_pre, ab_h, fh_w2, fh_b2, flow8);
    mask_combine_mfma<<<256, 1024, 0, stream>>>(m_frag, w2f, mk_b2, flow8, out);
}